// Round 2
// baseline (545.861 us; speedup 1.0000x reference)
//
#include <hip/hip_runtime.h>

#define NC 8192
#define NT 4096
#define NLAGS 103
#define WS_STRIDE 104
#define XBASE (NC*NLAGS)

// ---------------- Kernel 1: per-channel cross-correlation ----------------
// Persistent blocks, CPB channels, double-buffered d1 in LDS, d2 in regs.
// Software-pipelined: B1(it1 d2) + NX(next d1) issued at epoch start,
// B0next(next channel it0 d2) issued mid-epoch -> every load has a full
// FMA block (~3.3k cy) in flight before use; ONE barrier per channel.
// Lag base -1: wave wv covers L = 28*wv + l - 1 (l=0..27), valid 0..102.
// d1s logical index for (k,L) = k + L + 1 -> window base k0+28wv (%4==0).
// P32 pad: +4 dwords per 32 -> lane stride 36 dwords, ~2-way on b128 (free).
#define PADL 52
#define PADR 60
#define P32(x) ((x) + (((x) >> 5) << 2))   // logical -> physical dword index
#define D1PA 4736          // phys span of 4208 logical, rounded to x16
#define CPB 4
#define LPW 28
#define REDS 29            // reduction row stride (odd: conflict-free)
#define REDF (4*32*REDS)   // 3712 floats dedicated reduction buffer
#define SMEMF (2*D1PA + REDF)   // 13184 floats = 52.7 KB -> 3 blocks/CU

__global__ __launch_bounds__(256, 3)
void xcorr_kernel(const float* __restrict__ g1, const float* __restrict__ g2,
                  float* __restrict__ ws) {
    __shared__ __align__(16) float smem[SMEMF];
    float* red_all = smem + 2*D1PA;
    const int tid  = threadIdx.x;
    const int wv   = tid >> 6;
    const int lane = tid & 63;
    const int c0   = blockIdx.x * CPB;
    const int klane = lane * 32;

    // zero pads of both d1 buffers ONCE (nothing clobbers them afterwards)
    #pragma unroll
    for (int bb = 0; bb < 2; ++bb) {
        float* buf = smem + bb * D1PA;
        if (tid < PADL) buf[P32(tid)] = 0.f;
        if (tid < PADR) buf[P32(PADL + NT + tid)] = 0.f;
    }
    // stage d1(c0) into buf0 (data at logical 52, %4==0: aligned b128)
    {
        const float4* r = (const float4*)(g1 + (size_t)c0 * NT);
        float4 v0 = r[tid], v1 = r[tid+256], v2 = r[tid+512], v3 = r[tid+768];
        const int x = PADL + 4*tid;
        *(float4*)&smem[P32(x)]        = v0;
        *(float4*)&smem[P32(x + 1024)] = v1;
        *(float4*)&smem[P32(x + 2048)] = v2;
        *(float4*)&smem[P32(x + 3072)] = v3;
    }
    __syncthreads();

    // first channel's it0 d2 (issued post-barrier: no drain stall)
    float4 B0[8];
    {
        const float* p = g2 + (size_t)c0 * NT + klane;
        #pragma unroll
        for (int t = 0; t < 8; ++t) B0[t] = *(const float4*)(p + 4*t);
    }

    #pragma unroll 1
    for (int ci = 0; ci < CPB; ++ci) {
        const int c = c0 + ci;
        float* cur  = smem + (ci & 1) * D1PA;
        float* nxtb = smem + ((ci & 1) ^ 1) * D1PA;
        const bool hasnext = (ci + 1 < CPB);

        // ---- epoch-start prefetch: NX (next d1) + B1 (this channel, it1) ----
        float4 NX0, NX1, NX2, NX3;
        if (hasnext) {
            const float4* r = (const float4*)(g1 + (size_t)(c + 1) * NT);
            NX0 = r[tid]; NX1 = r[tid+256]; NX2 = r[tid+512]; NX3 = r[tid+768];
        }
        float4 B1[8];
        {
            const float* p = g2 + (size_t)c * NT + 2048 + klane;
            #pragma unroll
            for (int t = 0; t < 8; ++t) B1[t] = *(const float4*)(p + 4*t);
        }
        __builtin_amdgcn_sched_barrier(0);   // pin prefetch issue above it0

        float acc[LPW];
        #pragma unroll
        for (int l = 0; l < LPW; ++l) acc[l] = 0.f;

        // ---- it0: k in [klane, klane+32) ----
        {
            const int ab = klane + 28*wv;            // %4==0: aligned b128
            float w[60];
            #pragma unroll
            for (int t = 0; t < 15; ++t) {
                float4 v = *(const float4*)&cur[P32(ab + 4*t)];
                w[4*t]=v.x; w[4*t+1]=v.y; w[4*t+2]=v.z; w[4*t+3]=v.w;
            }
            float b[32];
            #pragma unroll
            for (int t = 0; t < 8; ++t) {
                b[4*t]=B0[t].x; b[4*t+1]=B0[t].y; b[4*t+2]=B0[t].z; b[4*t+3]=B0[t].w;
            }
            #pragma unroll
            for (int j = 0; j < 32; ++j)
                #pragma unroll
                for (int l = 0; l < LPW; ++l)
                    acc[l] = fmaf(w[l+j], b[j], acc[l]);
        }

        // ---- mid-epoch: retire NX to LDS, then prefetch next channel's B0 ----
        if (hasnext) {
            const int x = PADL + 4*tid;
            *(float4*)&nxtb[P32(x)]        = NX0;
            *(float4*)&nxtb[P32(x + 1024)] = NX1;
            *(float4*)&nxtb[P32(x + 2048)] = NX2;
            *(float4*)&nxtb[P32(x + 3072)] = NX3;
            const float* p = g2 + (size_t)(c + 1) * NT + klane;
            #pragma unroll
            for (int t = 0; t < 8; ++t) B0[t] = *(const float4*)(p + 4*t);
            __builtin_amdgcn_sched_barrier(0);   // pin B0next issue above it1
        }

        // ---- it1: k in [2048+klane, +32) ----
        {
            const int ab = 2048 + klane + 28*wv;
            float w[60];
            #pragma unroll
            for (int t = 0; t < 15; ++t) {
                float4 v = *(const float4*)&cur[P32(ab + 4*t)];
                w[4*t]=v.x; w[4*t+1]=v.y; w[4*t+2]=v.z; w[4*t+3]=v.w;
            }
            float b[32];
            #pragma unroll
            for (int t = 0; t < 8; ++t) {
                b[4*t]=B1[t].x; b[4*t+1]=B1[t].y; b[4*t+2]=B1[t].z; b[4*t+3]=B1[t].w;
            }
            #pragma unroll
            for (int j = 0; j < 32; ++j)
                #pragma unroll
                for (int l = 0; l < LPW; ++l)
                    acc[l] = fmaf(w[l+j], b[j], acc[l]);
        }

        // ---- barrier-free reduction in dedicated LDS (same-wave ordering) ----
        #pragma unroll
        for (int l = 0; l < LPW; ++l) acc[l] += __shfl_down(acc[l], 32);
        float* red = red_all + wv * (32*REDS);
        if (lane < 32) {
            #pragma unroll
            for (int l = 0; l < LPW; ++l) red[lane*REDS + l] = acc[l];
        }
        if (lane < LPW) {
            float s = 0.f;
            #pragma unroll
            for (int r = 0; r < 32; ++r) s += red[r*REDS + lane];
            const int L = 28*wv + lane - 1;
            if (L >= 0 && L < NLAGS) ws[(size_t)c * WS_STRIDE + L] = s;
        }
        __syncthreads();   // d1 buffer swap; all outstanding loads are old
    }
}

// -------- Kernel 2: moving average across channels + pick max|R| --------
#define TS 112   // tile stride (16*7: rows alias 2-way = free)
__global__ __launch_bounds__(256, 4)
void ma_pick_kernel(const float* __restrict__ ws, float* __restrict__ out) {
    __shared__ float tile[52*TS];
    __shared__ float matile[32*TS];
    const int tid = threadIdx.x;
    const int c0  = blockIdx.x * 32;

    for (int i = tid; i < 52*TS; i += 256) {
        int r   = i / TS;
        int col = i - r*TS;
        int g   = c0 - 10 + r;
        float v = 0.f;
        if (g >= 0 && g < NC && col < NLAGS) v = ws[(size_t)g*WS_STRIDE + col];
        tile[i] = v;
    }
    __syncthreads();

    {   // rolling 20-channel window sum; thread = one lag, 16 channels
        const int l = tid & 127;
        const int h = tid >> 7;
        if (l < NLAGS) {
            const int cc0 = h * 16;
            float s = 0.f;
            #pragma unroll
            for (int r = 0; r < 20; ++r) s += tile[(cc0 + r)*TS + l];
            #pragma unroll 1
            for (int cc = cc0; cc < cc0 + 16; ++cc) {
                float ma = s / 20.0f;
                matile[cc*TS + l] = ma;
                out[(size_t)(c0 + cc)*NLAGS + l] = ma;   // coalesced across l
                s += tile[(cc + 20)*TS + l] - tile[cc*TS + l];
            }
        }
    }
    __syncthreads();

    // per-channel argmax|R| (first-index tie-break), max, min
    const int wv = tid >> 6, lane = tid & 63;
    #pragma unroll 1
    for (int s8 = 0; s8 < 8; ++s8) {
        const int cc = wv*8 + s8;
        float v1 = matile[cc*TS + lane];
        float a1 = fabsf(v1);
        int   i1 = lane;
        float vmx = v1, vmn = v1;
        if (lane < NLAGS - 64) {                 // second element: l = lane+64
            float v2 = matile[cc*TS + 64 + lane];
            float a2 = fabsf(v2);
            vmx = fmaxf(vmx, v2); vmn = fminf(vmn, v2);
            if (a2 > a1) { a1 = a2; i1 = 64 + lane; v1 = v2; }
        }
        #pragma unroll
        for (int d = 32; d >= 1; d >>= 1) {
            float oa  = __shfl_xor(a1, d);
            int   oi  = __shfl_xor(i1, d);
            float ov  = __shfl_xor(v1, d);
            float omx = __shfl_xor(vmx, d);
            float omn = __shfl_xor(vmn, d);
            vmx = fmaxf(vmx, omx);
            vmn = fminf(vmn, omn);
            if (oa > a1 || (oa == a1 && oi < i1)) { a1 = oa; i1 = oi; v1 = ov; }
        }
        if (lane == 0) {
            const int ch = c0 + cc;
            out[XBASE + ch]        = v1;                         // vmain
            out[XBASE + NC + ch]   = (v1 >= 0.f) ? vmn : vmx;    // vside
            out[XBASE + 2*NC + ch] = (float)(i1 - 51) * 0.01f;   // tmax
        }
    }
}

extern "C" void kernel_launch(void* const* d_in, const int* in_sizes, int n_in,
                              void* d_out, int out_size, void* d_ws, size_t ws_size,
                              hipStream_t stream) {
    const float* g1 = (const float*)d_in[0];
    const float* g2 = (const float*)d_in[1];
    float* out = (float*)d_out;
    float* ws  = (float*)d_ws;   // 8192*104*4 = 3.4 MB scratch

    hipLaunchKernelGGL(xcorr_kernel, dim3(NC/CPB), dim3(256), 0, stream, g1, g2, ws);
    hipLaunchKernelGGL(ma_pick_kernel, dim3(NC/32), dim3(256), 0, stream, ws, out);
}

// Round 3
// 314.653 us; speedup vs baseline: 1.7348x; 1.7348x over previous
//
#include <hip/hip_runtime.h>

#define NC 8192
#define NT 4096
#define NLAGS 103
#define WS_STRIDE 104
#define XBASE (NC*NLAGS)

// ---------------- Kernel 1: per-channel cross-correlation ----------------
// One block per channel. d1 (zero-padded) and d2 both live in LDS, stored
// with a 128-B-row XOR granule swizzle: phys = b ^ (((b>>7)&7)<<4).
// d2 is staged by global_load_lds (linear dest, PRE-SWIZZLED per-lane global
// source -> zero VGPR cost, async). d1 is reg-staged with swizzled
// ds_write_b128 (needs the zero pads). All b128 reads then land 2-way on
// banks (free). Lag base -1: wave wv covers L = 28*wv + l - 1, valid 0..102;
// d1s logical dword for (k,L) = k + L + 1 -> window base k0 + 28*wv (%4==0).
#define D1LOG 4208       // 52 left zeros + 4096 data + 60 right zeros
#define D1DW  4224       // rounded to 128-B rows
#define D2DW  4096
#define REDS  29         // reduction row stride (odd: conflict-free)
#define SMEMF (D1DW + D2DW)   // 8320 floats = 33.3 KB -> 4 blocks/CU

__device__ __forceinline__ int swz(int b) {      // byte-granule XOR swizzle
    return b ^ (((b >> 7) & 7) << 4);
}

__global__ __launch_bounds__(256, 4)
void xcorr_kernel(const float* __restrict__ g1, const float* __restrict__ g2,
                  float* __restrict__ ws) {
    __shared__ __align__(128) float smem[SMEMF];
    char* d1b = (char*)smem;                 // byte views; offsets are
    char* d2b = (char*)(smem + D1DW);        // buffer-relative (128-B aligned)
    const int tid  = threadIdx.x;
    const int wv   = tid >> 6;
    const int lane = tid & 63;
    const int c    = blockIdx.x;
    const float* g1c = g1 + (size_t)c * NT;
    const float* g2c = g2 + (size_t)c * NT;

    // ---- d2 -> LDS: async DMA, source pre-swizzled so linear dest is
    //      equivalent to a swizzled store.  (O>>7)&7 == lane>>3 here. ----
    #pragma unroll
    for (int t = 0; t < 4; ++t) {
        const int O = 4096*wv + 1024*t + 16*lane;     // this lane's dest byte
        const int S = O ^ ((lane >> 3) << 4);         // swizzled source byte
        __builtin_amdgcn_global_load_lds(
            (const float*)((const char*)g2c + S),
            (float*)(d2b + 4096*wv + 1024*t),         // wave-uniform base
            16, 0, 0);
    }

    // ---- d1 -> regs -> swizzled LDS (pads need manual writes anyway) ----
    {
        const float4* r = (const float4*)g1c;
        float4 v0 = r[tid], v1 = r[tid+256], v2 = r[tid+512], v3 = r[tid+768];
        if (tid < 52) *(float*)(d1b + swz(4*tid)) = 0.f;              // left pad
        if (tid < 60) *(float*)(d1b + swz(4*(4148 + tid))) = 0.f;     // right pad
        const int B = 208 + 16*tid;          // logical byte of data granule
        *(float4*)(d1b + swz(B))         = v0;
        *(float4*)(d1b + swz(B + 4096))  = v1;
        *(float4*)(d1b + swz(B + 8192))  = v2;
        *(float4*)(d1b + swz(B + 12288)) = v3;
    }
    __syncthreads();   // vmcnt(0) drain => DMA landed; lgkm => d1 writes done

    float acc[28];
    #pragma unroll
    for (int l = 0; l < 28; ++l) acc[l] = 0.f;

    #pragma unroll 1
    for (int it = 0; it < 2; ++it) {
        const int k0 = 2048*it + 32*lane;
        float b[32];                         // d2[k0 .. k0+31]
        {
            const int base = 128*lane + 8192*it;
            const int sx   = (lane & 7) << 4;
            #pragma unroll
            for (int t = 0; t < 8; ++t) {
                float4 v = *(const float4*)(d2b + ((base + 16*t) ^ sx));
                b[4*t]=v.x; b[4*t+1]=v.y; b[4*t+2]=v.z; b[4*t+3]=v.w;
            }
        }
        float w[60];                         // d1s[k0+28wv .. +59]
        {
            const int xb = 4*(k0 + 28*wv);   // %16 == 0
            #pragma unroll
            for (int t = 0; t < 15; ++t) {
                float4 v = *(const float4*)(d1b + swz(xb + 16*t));
                w[4*t]=v.x; w[4*t+1]=v.y; w[4*t+2]=v.z; w[4*t+3]=v.w;
            }
        }
        #pragma unroll
        for (int j = 0; j < 32; ++j)
            #pragma unroll
            for (int l = 0; l < 28; ++l)
                acc[l] = fmaf(w[l+j], b[j], acc[l]);
    }

    // ---- cross-lane reduction; reuse dead d2 buffer as scratch ----
    __syncthreads();                         // all d2/d1 reads complete
    #pragma unroll
    for (int l = 0; l < 28; ++l) acc[l] += __shfl_down(acc[l], 32);
    float* red = (float*)d2b + wv * (32*REDS);   // 4*928 = 3712 <= 4096
    if (lane < 32) {
        #pragma unroll
        for (int l = 0; l < 28; ++l) red[lane*REDS + l] = acc[l];
    }
    // same-wave DS ordering: no barrier needed before the read-back
    if (lane < 28) {
        float s = 0.f;
        #pragma unroll
        for (int r = 0; r < 32; ++r) s += red[r*REDS + lane];
        const int L = 28*wv + lane - 1;
        if (L >= 0 && L < NLAGS) ws[(size_t)c * WS_STRIDE + L] = s;
    }
}

// -------- Kernel 2: moving average across channels + pick max|R| --------
#define TS 112   // tile stride (16*7: rows alias 2-way = free)
__global__ __launch_bounds__(256, 4)
void ma_pick_kernel(const float* __restrict__ ws, float* __restrict__ out) {
    __shared__ float tile[52*TS];
    __shared__ float matile[32*TS];
    const int tid = threadIdx.x;
    const int c0  = blockIdx.x * 32;

    for (int i = tid; i < 52*TS; i += 256) {
        int r   = i / TS;
        int col = i - r*TS;
        int g   = c0 - 10 + r;
        float v = 0.f;
        if (g >= 0 && g < NC && col < NLAGS) v = ws[(size_t)g*WS_STRIDE + col];
        tile[i] = v;
    }
    __syncthreads();

    {   // rolling 20-channel window sum; thread = one lag, 16 channels
        const int l = tid & 127;
        const int h = tid >> 7;
        if (l < NLAGS) {
            const int cc0 = h * 16;
            float s = 0.f;
            #pragma unroll
            for (int r = 0; r < 20; ++r) s += tile[(cc0 + r)*TS + l];
            #pragma unroll 1
            for (int cc = cc0; cc < cc0 + 16; ++cc) {
                float ma = s / 20.0f;
                matile[cc*TS + l] = ma;
                out[(size_t)(c0 + cc)*NLAGS + l] = ma;   // coalesced across l
                s += tile[(cc + 20)*TS + l] - tile[cc*TS + l];
            }
        }
    }
    __syncthreads();

    // per-channel argmax|R| (first-index tie-break), max, min
    const int wv = tid >> 6, lane = tid & 63;
    #pragma unroll 1
    for (int s8 = 0; s8 < 8; ++s8) {
        const int cc = wv*8 + s8;
        float v1 = matile[cc*TS + lane];
        float a1 = fabsf(v1);
        int   i1 = lane;
        float vmx = v1, vmn = v1;
        if (lane < NLAGS - 64) {                 // second element: l = lane+64
            float v2 = matile[cc*TS + 64 + lane];
            float a2 = fabsf(v2);
            vmx = fmaxf(vmx, v2); vmn = fminf(vmn, v2);
            if (a2 > a1) { a1 = a2; i1 = 64 + lane; v1 = v2; }
        }
        #pragma unroll
        for (int d = 32; d >= 1; d >>= 1) {
            float oa  = __shfl_xor(a1, d);
            int   oi  = __shfl_xor(i1, d);
            float ov  = __shfl_xor(v1, d);
            float omx = __shfl_xor(vmx, d);
            float omn = __shfl_xor(vmn, d);
            vmx = fmaxf(vmx, omx);
            vmn = fminf(vmn, omn);
            if (oa > a1 || (oa == a1 && oi < i1)) { a1 = oa; i1 = oi; v1 = ov; }
        }
        if (lane == 0) {
            const int ch = c0 + cc;
            out[XBASE + ch]        = v1;                         // vmain
            out[XBASE + NC + ch]   = (v1 >= 0.f) ? vmn : vmx;    // vside
            out[XBASE + 2*NC + ch] = (float)(i1 - 51) * 0.01f;   // tmax
        }
    }
}

extern "C" void kernel_launch(void* const* d_in, const int* in_sizes, int n_in,
                              void* d_out, int out_size, void* d_ws, size_t ws_size,
                              hipStream_t stream) {
    const float* g1 = (const float*)d_in[0];
    const float* g2 = (const float*)d_in[1];
    float* out = (float*)d_out;
    float* ws  = (float*)d_ws;   // 8192*104*4 = 3.4 MB scratch

    hipLaunchKernelGGL(xcorr_kernel, dim3(NC), dim3(256), 0, stream, g1, g2, ws);
    hipLaunchKernelGGL(ma_pick_kernel, dim3(NC/32), dim3(256), 0, stream, ws, out);
}